// Round 7
// baseline (293.320 us; speedup 1.0000x reference)
//
#include <hip/hip_runtime.h>

typedef _Float16 half_t;
typedef _Float16 half2_t __attribute__((ext_vector_type(2)));

#define BB 4
#define NN 1024
#define NH 8
#define KD 16
#define ID 128
#define ED 128

static constexpr size_t OUT_SZ   = (size_t)BB * NN * ED;       // 524288
static constexpr size_t ATT_SZ   = (size_t)NH * BB * NN * NN;  // 33554432
static constexpr size_t OFF_OSS  = OUT_SZ;
static constexpr size_t OFF_ST   = OUT_SZ + ATT_SZ;
static constexpr size_t HSTRIDE  = (size_t)BB * NN * NN;       // per-head stride in (h,b,n,m)

#define LGW 1032   // f16 elements per logits row (1024 + 8 pad)

__device__ __forceinline__ float fdot2u(unsigned int a, unsigned int b, float c) {
    union { unsigned int u; half2_t h; } ua, ub;
    ua.u = a; ub.u = b;
    return __builtin_amdgcn_fdot2(ua.h, ub.h, c, false);
}

// ---------------- Kernel 1: QKV projection ----------------
// Qh  [ (b*N+n)*128 + h*16+k ]                       (f16, natural k-pair u32 layout)
// Kp  [ ((b*8+h)*8+kp)*N + n ] u32 = (K[n][2kp],K[n][2kp+1])   (k-pair packed along n)
// Vt  [ ((b*8+h)*16+v)*N + n ]                       (f16, n-major rows for fdot2 PV)
__global__ __launch_bounds__(128) void qkv_kernel(
    const float* __restrict__ q,  const float* __restrict__ Wq,
    const float* __restrict__ Wk, const float* __restrict__ Wv,
    half_t* __restrict__ Qh, half_t* __restrict__ Kp, half_t* __restrict__ Vt)
{
    const int bn = blockIdx.x;           // 0..4095
    const int j  = threadIdx.x;          // 0..127 -> (h,k)
    const int h  = j >> 4, k = j & 15;
    const int b  = bn >> 10, n = bn & 1023;

    __shared__ float qrow[ID];
    qrow[j] = q[(size_t)bn * ID + j];
    __syncthreads();

    const float* wq = Wq + h * ID * KD + k;
    const float* wk = Wk + h * ID * KD + k;
    const float* wv = Wv + h * ID * KD + k;
    float aq = 0.f, ak = 0.f, av = 0.f;
#pragma unroll
    for (int i = 0; i < ID; ++i) {
        float x = qrow[i];
        aq = fmaf(x, wq[i * KD], aq);
        ak = fmaf(x, wk[i * KD], ak);
        av = fmaf(x, wv[i * KD], av);
    }
    Qh[(size_t)bn * 128 + j] = (half_t)aq;
    Kp[((size_t)((b * NH + h) * 8 + (k >> 1)) * NN + n) * 2 + (k & 1)] = (half_t)ak;
    Vt[((size_t)((b * NH + h) * KD + k)) * NN + n] = (half_t)av;
}

// ---------------- Kernel 2: fused logits+MLP+softmax+PV+proj + passthrough ----------------
__global__ __launch_bounds__(256, 8) void fused_kernel(
    const float* __restrict__ oss, const float* __restrict__ st,
    const half_t* __restrict__ Qh, const unsigned int* __restrict__ Kp,
    const half_t* __restrict__ Vt,
    const float* __restrict__ w1,  const float* __restrict__ b1,
    const float* __restrict__ w2,  const float* __restrict__ b2,
    const float* __restrict__ Wout, float* __restrict__ out)
{
    const int n   = blockIdx.x;
    const int b   = blockIdx.y;
    const int tid = threadIdx.x;

    __shared__ __align__(16) half_t lg[NH * LGW];   // 16.1 KB f16 logits/weights
    __shared__ unsigned int qsh[64];
    __shared__ float wred[4][8];
    __shared__ float wsum[4][8];
    __shared__ float headsSh[128];

    if (tid < 64) qsh[tid] =
        reinterpret_cast<const unsigned int*>(Qh + ((size_t)(b * NN + n)) * 128)[tid];
    __syncthreads();

    const int m0 = tid * 4;                         // thread owns m0..m0+3
    const size_t bn_off = ((size_t)(b * NN + n)) * NN;

    // layer-1 accumulators, streamed over h
    float y[4][8];
#pragma unroll
    for (int mo = 0; mo < 4; ++mo)
#pragma unroll
        for (int o = 0; o < 8; ++o) y[mo][o] = b1[o];

#pragma unroll 1
    for (int h = 0; h < 8; ++h) {
        const size_t idx = (size_t)h * HSTRIDE + bn_off + (size_t)m0;
        const float4 sv = *reinterpret_cast<const float4*>(st + idx);
        const float4 ov = *reinterpret_cast<const float4*>(oss + idx);
        *reinterpret_cast<float4*>(out + OFF_ST + idx)  = sv;   // st_edge passthrough
        *reinterpret_cast<float4*>(out + OFF_OSS + idx) = ov;   // oss passthrough
        const float svv[4] = {sv.x, sv.y, sv.z, sv.w};
        const float ovv[4] = {ov.x, ov.y, ov.z, ov.w};

        // QK^T for 4 m: k-pair packed, coalesced uint4 loads (4 consecutive n)
        const unsigned int* kb = Kp + ((size_t)((b * NH + h) * 8)) * NN + m0;
        float acc[4] = {0.f, 0.f, 0.f, 0.f};
#pragma unroll
        for (int kp = 0; kp < 8; ++kp) {
            const uint4 k4 = *reinterpret_cast<const uint4*>(kb + (size_t)kp * NN);
            const unsigned int qp = qsh[h * 8 + kp];
            acc[0] = fdot2u(k4.x, qp, acc[0]);
            acc[1] = fdot2u(k4.y, qp, acc[1]);
            acc[2] = fdot2u(k4.z, qp, acc[2]);
            acc[3] = fdot2u(k4.w, qp, acc[3]);
        }

        float w1c[8], w1o[8];                       // uniform -> SGPRs
#pragma unroll
        for (int o = 0; o < 8; ++o) { w1c[o] = w1[o * 16 + h]; w1o[o] = w1[o * 16 + 8 + h]; }
#pragma unroll
        for (int mo = 0; mo < 4; ++mo) {
            const float c = (acc[mo] + svv[mo]) * 0.25f;   // (QK + st) * 1/sqrt(16)
#pragma unroll
            for (int o = 0; o < 8; ++o)
                y[mo][o] = fmaf(c, w1c[o], fmaf(ovv[mo], w1o[o], y[mo][o]));
        }
    }

    // ---- layer 2 -> f16 logits in LDS + per-thread max ----
    float lgv[8][4];
#pragma unroll
    for (int mo = 0; mo < 4; ++mo) {
        float z[8];
#pragma unroll
        for (int o = 0; o < 8; ++o) z[o] = fmaxf(y[mo][o], 0.f);
#pragma unroll
        for (int p = 0; p < 8; ++p) {
            float a = b2[p];
#pragma unroll
            for (int o = 0; o < 8; ++o) a = fmaf(z[o], w2[p * 8 + o], a);
            lgv[p][mo] = a;
        }
    }
    float tmax[8];
#pragma unroll
    for (int p = 0; p < 8; ++p) {
        union { uint2 u; half_t h4[4]; } pk;
#pragma unroll
        for (int mo = 0; mo < 4; ++mo) pk.h4[mo] = (half_t)lgv[p][mo];
        *reinterpret_cast<uint2*>(&lg[p * LGW + m0]) = pk.u;
        tmax[p] = fmaxf(fmaxf(lgv[p][0], lgv[p][1]), fmaxf(lgv[p][2], lgv[p][3]));
    }
#pragma unroll
    for (int p = 0; p < 8; ++p)
#pragma unroll
        for (int s = 32; s > 0; s >>= 1)
            tmax[p] = fmaxf(tmax[p], __shfl_xor(tmax[p], s));
    const int wv = tid >> 6;
    if ((tid & 63) == 0) {
#pragma unroll
        for (int p = 0; p < 8; ++p) wred[wv][p] = tmax[p];
    }
    __syncthreads();

    float bmax[8];
#pragma unroll
    for (int p = 0; p < 8; ++p)
        bmax[p] = fmaxf(fmaxf(wred[0][p], wred[1][p]), fmaxf(wred[2][p], wred[3][p]));

    // ---- exp in place (f16) + per-thread sums ----
    float psum[8];
#pragma unroll
    for (int p = 0; p < 8; ++p) {
        union { uint2 u; half_t h4[4]; } r;
        r.u = *reinterpret_cast<const uint2*>(&lg[p * LGW + m0]);
        const float e0 = __expf((float)r.h4[0] - bmax[p]);
        const float e1 = __expf((float)r.h4[1] - bmax[p]);
        const float e2 = __expf((float)r.h4[2] - bmax[p]);
        const float e3 = __expf((float)r.h4[3] - bmax[p]);
        psum[p] = (e0 + e1) + (e2 + e3);
        union { uint2 u; half_t h4[4]; } w;
        w.h4[0] = (half_t)e0; w.h4[1] = (half_t)e1;
        w.h4[2] = (half_t)e2; w.h4[3] = (half_t)e3;
        *reinterpret_cast<uint2*>(&lg[p * LGW + m0]) = w.u;
    }
#pragma unroll
    for (int p = 0; p < 8; ++p)
#pragma unroll
        for (int s = 32; s > 0; s >>= 1)
            psum[p] += __shfl_xor(psum[p], s);
    if ((tid & 63) == 0) {
#pragma unroll
        for (int p = 0; p < 8; ++p) wsum[wv][p] = psum[p];
    }
    __syncthreads();

    // ---- PV: 4-lane group per (h,v); fdot2 on n-major V rows ----
    {
        const int g   = tid >> 2;          // 0..63
        const int h   = g >> 3;            // 0..7
        const int vb_ = g & 7;             // handles v = vb_, vb_+8
        const int sub = tid & 3;
        float res[2];
#pragma unroll
        for (int vs = 0; vs < 2; ++vs) {
            const int v = vb_ + vs * 8;
            const unsigned int* vr = reinterpret_cast<const unsigned int*>(
                Vt + ((size_t)((b * NH + h) * KD + v)) * NN);
            float acc = 0.f;
#pragma unroll 4
            for (int j = 0; j < 32; ++j) {
                const uint4 vv = *reinterpret_cast<const uint4*>(vr + sub * 4 + 16 * j);
                const uint4 ww = *reinterpret_cast<const uint4*>(&lg[h * LGW + sub * 8 + 32 * j]);
                acc = fdot2u(vv.x, ww.x, acc);
                acc = fdot2u(vv.y, ww.y, acc);
                acc = fdot2u(vv.z, ww.z, acc);
                acc = fdot2u(vv.w, ww.w, acc);
            }
            acc += __shfl_xor(acc, 1);
            acc += __shfl_xor(acc, 2);
            res[vs] = acc;
        }
        if (sub == 0) {
            const float s = (wsum[0][h] + wsum[1][h]) + (wsum[2][h] + wsum[3][h]);
            const float r = 1.0f / s;
            headsSh[h * 16 + vb_ + 0] = res[0] * r;
            headsSh[h * 16 + vb_ + 8] = res[1] * r;
        }
    }
    __syncthreads();

    // ---- output projection: out[b,n,e] = sum_hv heads[hv] * Wout[hv,e] ----
    {
        const int e = tid & 127, hf2 = tid >> 7;
        float a = 0.f;
#pragma unroll
        for (int hv = 0; hv < 64; ++hv) {
            const int i = hf2 * 64 + hv;
            a = fmaf(headsSh[i], Wout[(size_t)i * 128 + e], a);
        }
        float* red = reinterpret_cast<float*>(lg);
        red[tid] = a;
        __syncthreads();
        if (tid < 128)
            out[((size_t)(b * NN + n)) * 128 + tid] = red[tid] + red[tid + 128];
    }
}

extern "C" void kernel_launch(void* const* d_in, const int* in_sizes, int n_in,
                              void* d_out, int out_size, void* d_ws, size_t ws_size,
                              hipStream_t stream) {
    const float* q    = (const float*)d_in[0];
    const float* oss  = (const float*)d_in[1];
    const float* st   = (const float*)d_in[2];
    const float* Wq   = (const float*)d_in[3];
    const float* Wk   = (const float*)d_in[4];
    const float* Wv   = (const float*)d_in[5];
    const float* w1   = (const float*)d_in[6];
    const float* b1   = (const float*)d_in[7];
    const float* w2   = (const float*)d_in[8];
    const float* b2   = (const float*)d_in[9];
    const float* Wout = (const float*)d_in[10];
    float* out = (float*)d_out;

    half_t* Qh = (half_t*)d_ws;                                   // 1 MB f16
    half_t* Kp = (half_t*)((char*)d_ws + 1u * 1024u * 1024u);     // 1 MB f16 (k-pair packed)
    half_t* Vt = (half_t*)((char*)d_ws + 2u * 1024u * 1024u);     // 1 MB f16 (n-major rows)

    qkv_kernel<<<dim3(BB * NN), dim3(128), 0, stream>>>(q, Wq, Wk, Wv, Qh, Kp, Vt);
    fused_kernel<<<dim3(NN, BB), dim3(256), 0, stream>>>(
        oss, st, Qh, (const unsigned int*)Kp, Vt,
        w1, b1, w2, b2, Wout, out);
}

// Round 8
// 225.160 us; speedup vs baseline: 1.3027x; 1.3027x over previous
//
#include <hip/hip_runtime.h>

typedef _Float16 half_t;
typedef _Float16 half2_t __attribute__((ext_vector_type(2)));

#define BB 4
#define NN 1024
#define NH 8
#define KD 16
#define ID 128
#define ED 128

static constexpr size_t OUT_SZ   = (size_t)BB * NN * ED;       // 524288
static constexpr size_t ATT_SZ   = (size_t)NH * BB * NN * NN;  // 33554432
static constexpr size_t OFF_OSS  = OUT_SZ;
static constexpr size_t OFF_ST   = OUT_SZ + ATT_SZ;
static constexpr size_t HSTRIDE  = (size_t)BB * NN * NN;       // per-head stride in (h,b,n,m)

#define LGW 1032   // f16 elements per logits row (1024 + 8 pad)

__device__ __forceinline__ float fdot2u(unsigned int a, unsigned int b, float c) {
    union { unsigned int u; half2_t h; } ua, ub;
    ua.u = a; ub.u = b;
    return __builtin_amdgcn_fdot2(ua.h, ub.h, c, false);
}

// ---------------- Kernel 1: QKV projection (R5 form) ----------------
// Qh  [ (b*N+n)*128 + h*16+k ]
// Kp  [ ((b*8+h)*8+kp)*N + n ] u32 = (K[n][2kp],K[n][2kp+1])
// Vp  [ ((b*8+h)*8+vp)*N + n ] u32 = (V[n][2vp],V[n][2vp+1])
__global__ __launch_bounds__(128) void qkv_kernel(
    const float* __restrict__ q,  const float* __restrict__ Wq,
    const float* __restrict__ Wk, const float* __restrict__ Wv,
    half_t* __restrict__ Qh, half_t* __restrict__ Kp, half_t* __restrict__ Vp)
{
    const int bn = blockIdx.x;           // 0..4095
    const int j  = threadIdx.x;          // 0..127 -> (h,k)
    const int h  = j >> 4, k = j & 15;
    const int b  = bn >> 10, n = bn & 1023;

    __shared__ float qrow[ID];
    qrow[j] = q[(size_t)bn * ID + j];
    __syncthreads();

    const float* wq = Wq + h * ID * KD + k;
    const float* wk = Wk + h * ID * KD + k;
    const float* wv = Wv + h * ID * KD + k;
    float aq = 0.f, ak = 0.f, av = 0.f;
#pragma unroll
    for (int i = 0; i < ID; ++i) {
        float x = qrow[i];
        aq = fmaf(x, wq[i * KD], aq);
        ak = fmaf(x, wk[i * KD], ak);
        av = fmaf(x, wv[i * KD], av);
    }
    Qh[(size_t)bn * 128 + j] = (half_t)aq;
    const size_t pr = ((size_t)((b * NH + h) * 8 + (k >> 1)) * NN + n) * 2 + (k & 1);
    Kp[pr] = (half_t)ak;
    Vp[pr] = (half_t)av;
}

// ---------------- Kernel 1b: coalesced transpose Vp -> Vt ----------------
// Vt [ ((b*8+h)*16+v)*N + n ]  (n-major rows for fdot2 PV)
__global__ __launch_bounds__(256) void vtrans_kernel(
    const unsigned int* __restrict__ Vp, half_t* __restrict__ Vt)
{
    const int bh  = blockIdx.x >> 2;     // 0..31
    const int nt  = blockIdx.x & 3;
    const int tid = threadIdx.x;
    const int n0  = nt * 256;

    __shared__ half_t t[16][264];        // 264 keeps 16B-aligned rows, breaks bank stride

#pragma unroll
    for (int vp = 0; vp < 8; ++vp) {
        union { unsigned int u; half_t h2[2]; } c;
        c.u = Vp[((size_t)(bh * 8 + vp)) * NN + n0 + tid];
        t[2 * vp + 0][tid] = c.h2[0];
        t[2 * vp + 1][tid] = c.h2[1];
    }
    __syncthreads();
#pragma unroll
    for (int rep = 0; rep < 2; ++rep) {
        const int cch = tid + rep * 256;
        const int row = cch >> 5, col = (cch & 31) * 8;
        const uint4 vv = *reinterpret_cast<const uint4*>(&t[row][col]);
        *reinterpret_cast<uint4*>(Vt + ((size_t)(bh * 16 + row)) * NN + n0 + col) = vv;
    }
}

// ---------------- Kernel 2: fused, NT=2 rows per block, 512 threads ----------------
__global__ __launch_bounds__(512, 8) void fused_kernel(
    const float* __restrict__ oss, const float* __restrict__ st,
    const half_t* __restrict__ Qh, const unsigned int* __restrict__ Kp,
    const half_t* __restrict__ Vt,
    const float* __restrict__ w1,  const float* __restrict__ b1,
    const float* __restrict__ w2,  const float* __restrict__ b2,
    const float* __restrict__ Wout, float* __restrict__ out)
{
    const int np  = blockIdx.x;          // row pair: n = np*2 + nr
    const int b   = blockIdx.y;
    const int tid = threadIdx.x;
    const int nr  = tid >> 8;            // 0: waves 0-3, 1: waves 4-7
    const int t8  = tid & 255;

    __shared__ __align__(16) half_t lg[2 * NH * LGW];   // 33 KB
    __shared__ unsigned int qsh[2][64];
    __shared__ float wred[8][8];
    __shared__ float wsum[8][8];
    __shared__ float headsSh[2][128];

    if (tid < 128) {
        const int r = tid >> 6;
        qsh[r][tid & 63] = reinterpret_cast<const unsigned int*>(
            Qh + ((size_t)(b * NN + np * 2 + r)) * 128)[tid & 63];
    }
    __syncthreads();

    const int n  = np * 2 + nr;
    const int m0 = t8 * 4;                              // thread owns m0..m0+3
    const size_t bn_off = ((size_t)(b * NN + n)) * NN;
    half_t* lgn = lg + nr * (NH * LGW);

    // layer-1 accumulators, streamed over h
    float y[4][8];
#pragma unroll
    for (int mo = 0; mo < 4; ++mo)
#pragma unroll
        for (int o = 0; o < 8; ++o) y[mo][o] = b1[o];

#pragma unroll 1
    for (int h = 0; h < 8; ++h) {
        const size_t idx = (size_t)h * HSTRIDE + bn_off + (size_t)m0;
        const float4 sv = *reinterpret_cast<const float4*>(st + idx);
        const float4 ov = *reinterpret_cast<const float4*>(oss + idx);
        *reinterpret_cast<float4*>(out + OFF_ST + idx)  = sv;   // st_edge passthrough
        *reinterpret_cast<float4*>(out + OFF_OSS + idx) = ov;   // oss passthrough
        const float svv[4] = {sv.x, sv.y, sv.z, sv.w};
        const float ovv[4] = {ov.x, ov.y, ov.z, ov.w};

        // QK^T for 4 m: k-pair packed, coalesced uint4 loads
        const unsigned int* kb = Kp + ((size_t)((b * NH + h) * 8)) * NN + m0;
        float acc[4] = {0.f, 0.f, 0.f, 0.f};
#pragma unroll
        for (int kp = 0; kp < 8; ++kp) {
            const uint4 k4 = *reinterpret_cast<const uint4*>(kb + (size_t)kp * NN);
            const unsigned int qp = qsh[nr][h * 8 + kp];
            acc[0] = fdot2u(k4.x, qp, acc[0]);
            acc[1] = fdot2u(k4.y, qp, acc[1]);
            acc[2] = fdot2u(k4.z, qp, acc[2]);
            acc[3] = fdot2u(k4.w, qp, acc[3]);
        }

        float w1c[8], w1o[8];                       // uniform -> SGPRs
#pragma unroll
        for (int o = 0; o < 8; ++o) { w1c[o] = w1[o * 16 + h]; w1o[o] = w1[o * 16 + 8 + h]; }
#pragma unroll
        for (int mo = 0; mo < 4; ++mo) {
            const float c = (acc[mo] + svv[mo]) * 0.25f;   // (QK + st) * 1/sqrt(16)
#pragma unroll
            for (int o = 0; o < 8; ++o)
                y[mo][o] = fmaf(c, w1c[o], fmaf(ovv[mo], w1o[o], y[mo][o]));
        }
    }

    // ---- layer 2 -> f16 logits in LDS + per-thread max ----
    float lgv[8][4];
#pragma unroll
    for (int mo = 0; mo < 4; ++mo) {
        float z[8];
#pragma unroll
        for (int o = 0; o < 8; ++o) z[o] = fmaxf(y[mo][o], 0.f);
#pragma unroll
        for (int p = 0; p < 8; ++p) {
            float a = b2[p];
#pragma unroll
            for (int o = 0; o < 8; ++o) a = fmaf(z[o], w2[p * 8 + o], a);
            lgv[p][mo] = a;
        }
    }
    float tmax[8];
#pragma unroll
    for (int p = 0; p < 8; ++p) {
        union { uint2 u; half_t h4[4]; } pk;
#pragma unroll
        for (int mo = 0; mo < 4; ++mo) pk.h4[mo] = (half_t)lgv[p][mo];
        *reinterpret_cast<uint2*>(&lgn[p * LGW + m0]) = pk.u;
        tmax[p] = fmaxf(fmaxf(lgv[p][0], lgv[p][1]), fmaxf(lgv[p][2], lgv[p][3]));
    }
#pragma unroll
    for (int p = 0; p < 8; ++p)
#pragma unroll
        for (int s = 32; s > 0; s >>= 1)
            tmax[p] = fmaxf(tmax[p], __shfl_xor(tmax[p], s));
    const int wv = tid >> 6;                            // 0..7
    if ((tid & 63) == 0) {
#pragma unroll
        for (int p = 0; p < 8; ++p) wred[wv][p] = tmax[p];
    }
    __syncthreads();

    float bmax[8];
#pragma unroll
    for (int p = 0; p < 8; ++p)
        bmax[p] = fmaxf(fmaxf(wred[nr * 4 + 0][p], wred[nr * 4 + 1][p]),
                        fmaxf(wred[nr * 4 + 2][p], wred[nr * 4 + 3][p]));

    // ---- exp in place (f16) + per-thread sums ----
    float psum[8];
#pragma unroll
    for (int p = 0; p < 8; ++p) {
        union { uint2 u; half_t h4[4]; } r;
        r.u = *reinterpret_cast<const uint2*>(&lgn[p * LGW + m0]);
        const float e0 = __expf((float)r.h4[0] - bmax[p]);
        const float e1 = __expf((float)r.h4[1] - bmax[p]);
        const float e2 = __expf((float)r.h4[2] - bmax[p]);
        const float e3 = __expf((float)r.h4[3] - bmax[p]);
        psum[p] = (e0 + e1) + (e2 + e3);
        union { uint2 u; half_t h4[4]; } w;
        w.h4[0] = (half_t)e0; w.h4[1] = (half_t)e1;
        w.h4[2] = (half_t)e2; w.h4[3] = (half_t)e3;
        *reinterpret_cast<uint2*>(&lgn[p * LGW + m0]) = w.u;
    }
#pragma unroll
    for (int p = 0; p < 8; ++p)
#pragma unroll
        for (int s = 32; s > 0; s >>= 1)
            psum[p] += __shfl_xor(psum[p], s);
    if ((tid & 63) == 0) {
#pragma unroll
        for (int p = 0; p < 8; ++p) wsum[wv][p] = psum[p];
    }
    __syncthreads();

    // ---- PV: per nr, 4-lane group per (h,v); fdot2 on n-major V rows ----
    {
        const int g   = t8 >> 2;           // 0..63
        const int h   = g >> 3;            // 0..7
        const int vb_ = g & 7;             // handles v = vb_, vb_+8
        const int sub = t8 & 3;
        float res[2];
#pragma unroll
        for (int vs = 0; vs < 2; ++vs) {
            const int v = vb_ + vs * 8;
            const unsigned int* vr = reinterpret_cast<const unsigned int*>(
                Vt + ((size_t)((b * NH + h) * KD + v)) * NN);
            float acc = 0.f;
#pragma unroll 4
            for (int j = 0; j < 32; ++j) {
                const uint4 vv = *reinterpret_cast<const uint4*>(vr + sub * 4 + 16 * j);
                const uint4 ww = *reinterpret_cast<const uint4*>(&lgn[h * LGW + sub * 8 + 32 * j]);
                acc = fdot2u(vv.x, ww.x, acc);
                acc = fdot2u(vv.y, ww.y, acc);
                acc = fdot2u(vv.z, ww.z, acc);
                acc = fdot2u(vv.w, ww.w, acc);
            }
            acc += __shfl_xor(acc, 1);
            acc += __shfl_xor(acc, 2);
            res[vs] = acc;
        }
        if (sub == 0) {
            const float s = (wsum[nr * 4 + 0][h] + wsum[nr * 4 + 1][h]) +
                            (wsum[nr * 4 + 2][h] + wsum[nr * 4 + 3][h]);
            const float r = 1.0f / s;
            headsSh[nr][h * 16 + vb_ + 0] = res[0] * r;
            headsSh[nr][h * 16 + vb_ + 8] = res[1] * r;
        }
    }
    __syncthreads();

    // ---- output projection ----
    {
        const int e = t8 & 127, hf2 = t8 >> 7;
        float a = 0.f;
#pragma unroll
        for (int hv = 0; hv < 64; ++hv) {
            const int i = hf2 * 64 + hv;
            a = fmaf(headsSh[nr][i], Wout[(size_t)i * 128 + e], a);
        }
        float* red = reinterpret_cast<float*>(lg);
        red[tid] = a;
        __syncthreads();
        if (t8 < 128)
            out[((size_t)(b * NN + n)) * 128 + t8] = red[nr * 256 + t8] + red[nr * 256 + 128 + t8];
    }
}

extern "C" void kernel_launch(void* const* d_in, const int* in_sizes, int n_in,
                              void* d_out, int out_size, void* d_ws, size_t ws_size,
                              hipStream_t stream) {
    const float* q    = (const float*)d_in[0];
    const float* oss  = (const float*)d_in[1];
    const float* st   = (const float*)d_in[2];
    const float* Wq   = (const float*)d_in[3];
    const float* Wk   = (const float*)d_in[4];
    const float* Wv   = (const float*)d_in[5];
    const float* w1   = (const float*)d_in[6];
    const float* b1   = (const float*)d_in[7];
    const float* w2   = (const float*)d_in[8];
    const float* b2   = (const float*)d_in[9];
    const float* Wout = (const float*)d_in[10];
    float* out = (float*)d_out;

    half_t* Qh = (half_t*)d_ws;                                   // 1 MB f16
    half_t* Kp = (half_t*)((char*)d_ws + 1u * 1024u * 1024u);     // 1 MB f16 (k-pair packed)
    half_t* Vp = (half_t*)((char*)d_ws + 2u * 1024u * 1024u);     // 1 MB f16 (v-pair packed)
    half_t* Vt = (half_t*)((char*)d_ws + 3u * 1024u * 1024u);     // 1 MB f16 (n-major rows)

    qkv_kernel<<<dim3(BB * NN), dim3(128), 0, stream>>>(q, Wq, Wk, Wv, Qh, Kp, Vp);
    vtrans_kernel<<<dim3(32 * 4), dim3(256), 0, stream>>>((const unsigned int*)Vp, Vt);
    fused_kernel<<<dim3(NN / 2, BB), dim3(512), 0, stream>>>(
        oss, st, Qh, (const unsigned int*)Kp, Vt,
        w1, b1, w2, b2, Wout, out);
}